// Round 19
// baseline (407.754 us; speedup 1.0000x reference)
//
#include <hip/hip_runtime.h>
#include <hip/hip_bf16.h>
#include <math.h>

#define B_ 32
#define H_ 56
#define W_ 56
#define N_ 3136
#define NT_ 100352

typedef short short8 __attribute__((ext_vector_type(8)));
typedef float f32x4 __attribute__((ext_vector_type(4)));

__device__ __forceinline__ unsigned short f2b(float f){
  union { float f; unsigned u; } v; v.f = f;
  return (unsigned short)((v.u + 0x7FFFu + ((v.u>>16)&1u)) >> 16);
}

#define LDSW(row, bo) ((unsigned)((row)*128 + ((bo) ^ (((row)&7)<<4))))

__device__ __forceinline__ short8 ldfrag(const char* base, int row, int kk){
  return *(const short8*)(base + LDSW(row, kk*2));
}
__device__ __forceinline__ f32x4 mfma16(short8 a, short8 b, f32x4 c){
  return __builtin_amdgcn_mfma_f32_16x16x32_bf16(a, b, c, 0, 0, 0);
}
__device__ __forceinline__ void gld16(void* lds, const void* g){
  __builtin_amdgcn_global_load_lds((__attribute__((address_space(1))) void*)g,
                                   (__attribute__((address_space(3))) void*)lds,
                                   16, 0, 0);
}

// ---------------- fused prep + transpose -----------------------------------
__global__ void prep_trans_kernel(
    const float* __restrict__ x, unsigned short* __restrict__ xt,
    const float* __restrict__ Wq, const float* __restrict__ Wk,
    const float* __restrict__ Wv, const float* __restrict__ Wkv1,
    const float* __restrict__ Wkv2, const float* __restrict__ sr1w,
    const float* __restrict__ sr2w, const float* __restrict__ rpw,
    const float* __restrict__ rpb, const float* __restrict__ rp12w,
    const float* __restrict__ rp12b, const float* __restrict__ dww,
    unsigned short* WqT, unsigned short* WkT, unsigned short* WvT,
    unsigned short* Wkv1T, unsigned short* Wkv2T,
    unsigned short* srw1, unsigned short* srw2,
    unsigned short* Acomb, float* bias_out)
{
  __shared__ float tile[64][65];
  if (blockIdx.x < 6272){
    int bn = blockIdx.x >> 2; int b = bn / 49; int n0 = (bn - b*49)*64;
    int c0 = (blockIdx.x & 3)*64;
    int t = threadIdx.x;
    {
      int cl = t >> 2, nq = t & 3;
      const float* src = x + ((size_t)(b*256 + c0 + cl))*N_ + n0 + nq*16;
#pragma unroll
      for (int j = 0; j < 4; j++){
        float4 v = *(const float4*)(src + j*4);
        tile[cl][nq*16 + j*4 + 0] = v.x;
        tile[cl][nq*16 + j*4 + 1] = v.y;
        tile[cl][nq*16 + j*4 + 2] = v.z;
        tile[cl][nq*16 + j*4 + 3] = v.w;
      }
    }
    __syncthreads();
    {
      int nl = t >> 2, cq = t & 3;
      unsigned short pk[16];
#pragma unroll
      for (int j=0;j<16;j++) pk[j] = f2b(tile[cq*16+j][nl]);
      unsigned short* dst = xt + ((size_t)(b*N_ + n0 + nl))*256 + c0 + cq*16;
      *(uint4*)dst = *(uint4*)&pk[0];
      *(uint4*)(dst+8) = *(uint4*)&pk[8];
    }
    return;
  }
  int idx = (blockIdx.x - 6272)*256 + threadIdx.x;
  const int stride = 2048*256;
  const int total = 5*65536 + 4194304 + 1048576 + 131072 + 256;
  for (int i = idx; i < total; i += stride) {
    int j = i;
    if (j < 5*65536) {
      int w = j >> 16, e = j & 65535;
      int o = e >> 8, c = e & 255;
      const float* src = (w==0)?Wq:(w==1)?Wk:(w==2)?Wv:(w==3)?Wkv1:Wkv2;
      unsigned short* dst = (w==0)?WqT:(w==1)?WkT:(w==2)?WvT:(w==3)?Wkv1T:Wkv2T;
      dst[o*256+c] = f2b(src[c*256+o]);
      continue;
    }
    j -= 5*65536;
    if (j < 4194304) {
      int o = j >> 14, rem = j & 16383, pos = rem >> 8, c = rem & 255;
      srw1[j] = f2b(sr1w[o*16384 + c*64 + pos]);
      continue;
    }
    j -= 4194304;
    if (j < 1048576) {
      int o = j >> 12, rem = j & 4095, pos = rem >> 8, c = rem & 255;
      srw2[j] = f2b(sr2w[o*4096 + c*16 + pos]);
      continue;
    }
    j -= 1048576;
    if (j < 131072) {
      int o = j >> 9, i2 = j & 511;
      float v = (i2 < 256) ? dww[o*2+0]*rpw[o*256+i2]
                           : dww[o*2+1]*rp12w[o*256+(i2-256)];
      Acomb[o*512+i2] = f2b(v);
      continue;
    }
    j -= 131072;
    bias_out[j] = dww[j*2+0]*rpb[j] + dww[j*2+1]*rp12b[j];
  }
}

// ---------------- qkv3 body (A resident, B full, min barriers) -------------
__device__ __forceinline__ void qkv3_body(
    const unsigned short* __restrict__ xt,
    const unsigned short* __restrict__ WqT, const unsigned short* __restrict__ WkT,
    const unsigned short* __restrict__ WvT,
    const float* __restrict__ bq, const float* __restrict__ bk, const float* __restrict__ bv,
    unsigned short* __restrict__ qbuf, unsigned short* __restrict__ KexpT,
    unsigned short* __restrict__ VT, float* __restrict__ s_q, float* __restrict__ s_k,
    int blkid, char* smem)
{
  char* At = smem;
  char* Bt = smem + 32768;
  float* redbuf = (float*)(smem + 65536);
  const int t = threadIdx.x, wave = t>>6, lane = t&63, l15 = lane&15, l4 = lane>>4;
  const int r0 = blkid*64;
  const int b = r0 / N_;
  const int nl0 = r0 - b*N_;

#pragma unroll
  for (int c4=0;c4<4;c4++)
#pragma unroll
    for (int j=0;j<2;j++){
      int chunk = j*256 + t; int row = chunk>>3, c8 = chunk&7;
      int c8s = c8 ^ (row&7);
      gld16(At + c4*8192 + (j*256 + wave*64)*16,
            xt + (size_t)(r0+row)*256 + c4*64 + c8s*8);
    }
  __syncthreads();

  for (int mat=0; mat<3; mat++){
    const unsigned short* BT = (mat==0)?WqT:(mat==1)?WkT:WvT;
    const float* bias = (mat==0)?bq:(mat==1)?bk:bv;
    const f32x4 vzero = {0.f,0.f,0.f,0.f};
    f32x4 acc[4][4];
#pragma unroll
    for (int i=0;i<4;i++)
#pragma unroll
      for (int j=0;j<4;j++) acc[i][j] = vzero;

    for (int k0c=0;k0c<4;k0c++){
#pragma unroll
      for (int j=0;j<8;j++){
        int chunk = j*256 + t; int row = chunk>>3, c8 = chunk&7;
        int c8s = c8 ^ (row&7);
        gld16(Bt + (j*256 + wave*64)*16, BT + (size_t)row*256 + k0c*64 + c8s*8);
      }
      __syncthreads();
#pragma unroll
      for (int ks=0;ks<2;ks++){
        short8 af[4], bfr[4];
#pragma unroll
        for (int mi=0;mi<4;mi++) af[mi]  = ldfrag(At + k0c*8192, mi*16 + l15, ks*32 + l4*8);
#pragma unroll
        for (int ni=0;ni<4;ni++) bfr[ni] = ldfrag(Bt, wave*64 + ni*16 + l15, ks*32 + l4*8);
#pragma unroll
        for (int mi=0;mi<4;mi++)
#pragma unroll
          for (int ni=0;ni<4;ni++)
            acc[mi][ni] = mfma16(af[mi], bfr[ni], acc[mi][ni]);
      }
      __syncthreads();
    }

    float bb4[4];
#pragma unroll
    for (int ni=0;ni<4;ni++) bb4[ni] = bias[wave*64 + ni*16 + l15];

    if (mat == 0) {
      float rs[4][4];
#pragma unroll
      for (int mi=0;mi<4;mi++)
#pragma unroll
        for (int r=0;r<4;r++) rs[mi][r] = 0.f;
#pragma unroll
      for (int mi=0;mi<4;mi++)
#pragma unroll
        for (int ni=0;ni<4;ni++)
#pragma unroll
          for (int r=0;r<4;r++){
            float e = __expf(acc[mi][ni][r] + bb4[ni]);
            acc[mi][ni][r] = e;
            rs[mi][r] += e;
          }
#pragma unroll
      for (int mi=0;mi<4;mi++)
#pragma unroll
        for (int r=0;r<4;r++){
          float s = rs[mi][r];
          s += __shfl_xor(s, 1); s += __shfl_xor(s, 2);
          s += __shfl_xor(s, 4); s += __shfl_xor(s, 8);
          rs[mi][r] = s;
        }
      if (l15 == 0){
#pragma unroll
        for (int mi=0;mi<4;mi++)
#pragma unroll
          for (int r=0;r<4;r++)
            redbuf[wave*64 + mi*16 + l4*4 + r] = rs[mi][r];
      }
      __syncthreads();
      unsigned short* qb = (unsigned short*)Bt;
#pragma unroll
      for (int mi=0;mi<4;mi++)
#pragma unroll
        for (int r=0;r<4;r++){
          int rr = mi*16 + l4*4 + r;
#pragma unroll
          for (int ni=0;ni<4;ni++)
            qb[rr*256 + wave*64 + ni*16 + l15] = f2b(acc[mi][ni][r]);
        }
      if (t < 64){
        s_q[r0 + t] = redbuf[t] + redbuf[64+t] + redbuf[128+t] + redbuf[192+t];
      }
      __syncthreads();
#pragma unroll
      for (int j=0;j<8;j++){
        int chunk = j*256 + t;
        int row = chunk >> 5, c8 = chunk & 31;
        *(uint4*)(qbuf + (size_t)(r0+row)*256 + c8*8) = *(const uint4*)(qb + row*256 + c8*8);
      }
      __syncthreads();
    } else {
      float cs[4] = {0.f,0.f,0.f,0.f};
#pragma unroll
      for (int mi=0;mi<4;mi++)
#pragma unroll
        for (int ni=0;ni<4;ni++)
#pragma unroll
          for (int r=0;r<4;r++){
            float v = acc[mi][ni][r] + bb4[ni];
            if (mat == 1){ v = __expf(v); cs[ni] += v; }
            int row = mi*16 + l4*4 + r;
            int col = wave*64 + ni*16 + l15;
            *(unsigned short*)(Bt + LDSW(col, row*2)) = f2b(v);
          }
      if (mat == 1){
#pragma unroll
        for (int ni=0;ni<4;ni++){
          float s = cs[ni];
          s += __shfl_xor(s, 16);
          s += __shfl_xor(s, 32);
          if (lane < 16) atomicAdd(&s_k[b*256 + wave*64 + ni*16 + lane], s);
        }
      }
      __syncthreads();
      unsigned short* ot = (mat==1) ? KexpT : VT;
#pragma unroll
      for (int j=0;j<8;j++){
        int chunk = j*256 + t;
        int c = chunk >> 3, n8 = chunk & 7;
        *(uint4*)(ot + ((size_t)b*256 + c)*N_ + nl0 + n8*8) = *(const uint4*)(Bt + LDSW(c, n8*16));
      }
      __syncthreads();
    }
  }
}

// ---------------- srconv body ----------------------------------------------
template<int S, int OW, int KW, int NSK, int MPB, int KTOT>
__device__ __forceinline__ void srconv_body(
    const unsigned short* __restrict__ xt, const unsigned short* __restrict__ wbf,
    float* __restrict__ part, int bid, char* At, char* Bt)
{
  const int KCH = KTOT / NSK;
  const int Mtot = B_*MPB;
  const int sk = bid % NSK, tile = bid / NSK;
  const int t = threadIdx.x, wave = t>>6, lane = t&63, l15 = lane&15, l4 = lane>>4;
  const f32x4 vzero = {0.f,0.f,0.f,0.f};
  f32x4 acc[4][4];
#pragma unroll
  for (int i=0;i<4;i++)
#pragma unroll
    for (int j=0;j<4;j++) acc[i][j] = vzero;

  size_t abase[2];
#pragma unroll
  for (int j=0;j<2;j++){
    int chunk = j*256 + t;
    int row = chunk >> 3, c8 = chunk & 7;
    int c8s = c8 ^ (row&7);
    int rowc = tile*64 + row; if (rowc > Mtot-1) rowc = Mtot-1;
    int b = rowc / MPB; int m = rowc - b*MPB;
    int p = m / OW; int q = m - p*OW;
    abase[j] = ((size_t)b*N_ + (size_t)(S*p)*W_ + S*q)*256 + c8s*8;
  }

  for (int kt = 0; kt < KCH; kt += 64){
    const int k0 = sk*KCH + kt;
    const int pos = k0 >> 8, cc = k0 & 255;
    const int dy = pos / KW, dx = pos - dy*KW;
    const size_t off = (size_t)(dy*W_ + dx)*256 + cc;
#pragma unroll
    for (int j=0;j<2;j++){
      gld16(At + (j*256 + wave*64)*16, xt + abase[j] + off);
    }
#pragma unroll
    for (int j=0;j<8;j++){
      int chunk = j*256 + t; int row = chunk>>3, c8 = chunk&7;
      int c8s = c8 ^ (row&7);
      gld16(Bt + (j*256 + wave*64)*16, wbf + (size_t)row*KTOT + k0 + c8s*8);
    }
    __syncthreads();
#pragma unroll
    for (int ks=0;ks<2;ks++){
      short8 af[4], bfr[4];
#pragma unroll
      for (int mi=0;mi<4;mi++) af[mi]  = ldfrag(At, mi*16 + l15, ks*32 + l4*8);
#pragma unroll
      for (int ni=0;ni<4;ni++) bfr[ni] = ldfrag(Bt, wave*64 + ni*16 + l15, ks*32 + l4*8);
#pragma unroll
      for (int mi=0;mi<4;mi++)
#pragma unroll
        for (int ni=0;ni<4;ni++)
          acc[mi][ni] = mfma16(af[mi], bfr[ni], acc[mi][ni]);
    }
    __syncthreads();
  }
#pragma unroll
  for (int mi=0;mi<4;mi++)
#pragma unroll
    for (int r=0;r<4;r++){
      int row = tile*64 + mi*16 + l4*4 + r;
      if (row < Mtot){
        size_t basep = ((size_t)sk*Mtot + row)*256;
#pragma unroll
        for (int ni=0;ni<4;ni++)
          part[basep + wave*64 + ni*16 + l15] = acc[mi][ni][r];
      }
    }
}

// ---------------- merged: qkv + srconv (independent work co-scheduled) -----
// grid 2376: r=bid%3, q=bid/3. r<2 -> qkv block 2q+r (if <1568);
// r==2 -> srconv block q (q<392: branch2; else branch1).
__global__ __launch_bounds__(256,2) void qkv_conv_kernel(
    const unsigned short* __restrict__ xt,
    const unsigned short* __restrict__ WqT, const unsigned short* __restrict__ WkT,
    const unsigned short* __restrict__ WvT,
    const float* __restrict__ bq, const float* __restrict__ bk, const float* __restrict__ bv,
    unsigned short* __restrict__ qbuf, unsigned short* __restrict__ KexpT,
    unsigned short* __restrict__ VT, float* __restrict__ s_q, float* __restrict__ s_k,
    const unsigned short* __restrict__ srw1, const unsigned short* __restrict__ srw2,
    float* __restrict__ x1part, float* __restrict__ x2part)
{
  __shared__ __align__(16) char smem[32768 + 32768 + 1024];
  const int r = blockIdx.x % 3, q = blockIdx.x / 3;
  if (r < 2){
    int qk = 2*q + r;
    if (qk >= 1568) return;
    qkv3_body(xt, WqT, WkT, WvT, bq, bk, bv, qbuf, KexpT, VT, s_q, s_k, qk, smem);
  } else {
    if (q < 392)
      srconv_body<4,14,4,4,196,4096>(xt, srw2, x2part, q, smem, smem+8192);
    else
      srconv_body<8,7,8,16,49,16384>(xt, srw1, x1part, q-392, smem, smem+8192);
  }
}

// ---------------- ctx main (split-K 7, XCD-local (b,sk) groups) ------------
__global__ __launch_bounds__(256,4) void ctxmain_kernel(
    const unsigned short* __restrict__ KexpT, const unsigned short* __restrict__ VT,
    float* __restrict__ part)
{
  __shared__ __align__(16) char smem[32768];
  char* At = smem; char* Bt = smem + 16384;
  const int orig = blockIdx.x;
  const int idx = (orig & 7)*112 + (orig >> 3);
  const int b = idx / 28; int rem = idx - b*28;
  const int sk = rem >> 2, y = rem & 3;
  const int mt = y >> 1, nt = y & 1;
  const int it0 = sk*7, it1 = it0+7;
  const int t = threadIdx.x;
  const int wave = t>>6, lane = t&63, l15 = lane&15, l4 = lane>>4;
  const int wm = (wave>>1)*64, wn = (wave&1)*64;
  const unsigned short* A  = KexpT + ((size_t)b*256 + mt*128)*N_;
  const unsigned short* Bv = VT + ((size_t)b*256 + nt*128)*N_;
  const f32x4 vzero = {0.f,0.f,0.f,0.f};
  f32x4 acc[4][4];
#pragma unroll
  for (int i=0;i<4;i++)
#pragma unroll
    for (int j=0;j<4;j++) acc[i][j] = vzero;

  for (int it=it0; it<it1; it++){
    const int k0 = it*64;
#pragma unroll
    for (int j=0;j<4;j++){
      int chunk = j*256 + t; int row = chunk>>3, c8 = chunk&7;
      int c8s = c8 ^ (row&7);
      gld16(At + (j*256 + wave*64)*16, A + (size_t)row*N_ + k0 + c8s*8);
    }
#pragma unroll
    for (int j=0;j<4;j++){
      int chunk = j*256 + t; int row = chunk>>3, c8 = chunk&7;
      int c8s = c8 ^ (row&7);
      gld16(Bt + (j*256 + wave*64)*16, Bv + (size_t)row*N_ + k0 + c8s*8);
    }
    __syncthreads();
#pragma unroll
    for (int ks=0;ks<2;ks++){
      short8 af[4], bfr[4];
#pragma unroll
      for (int mi=0;mi<4;mi++) af[mi]  = ldfrag(At, wm + mi*16 + l15, ks*32 + l4*8);
#pragma unroll
      for (int ni=0;ni<4;ni++) bfr[ni] = ldfrag(Bt, wn + ni*16 + l15, ks*32 + l4*8);
#pragma unroll
      for (int mi=0;mi<4;mi++)
#pragma unroll
        for (int ni=0;ni<4;ni++)
          acc[mi][ni] = mfma16(af[mi], bfr[ni], acc[mi][ni]);
    }
    __syncthreads();
  }
#pragma unroll
  for (int mi=0;mi<4;mi++)
#pragma unroll
    for (int r=0;r<4;r++){
      int kg = mt*128 + wm + mi*16 + l4*4 + r;
      size_t basep = (((size_t)sk*B_ + b)*256 + kg)*256 + nt*128 + wn;
#pragma unroll
      for (int ni=0;ni<4;ni++)
        part[basep + ni*16 + l15] = acc[mi][ni][r];
    }
}

// ---------------- LN+GELU body ---------------------------------------------
__device__ __forceinline__ void lngelu_body(
    const float* __restrict__ part, const float* __restrict__ srb,
    const float* __restrict__ g, const float* __restrict__ bb,
    unsigned short* __restrict__ out, int M, int nsk, int Mtot, int bid,
    float* red)
{
  int b = bid / M, m = bid - b*M;
  int c = threadIdx.x;
  float v = srb[c];
  for (int s=0;s<nsk;s++) v += part[((size_t)s*Mtot + b*M + m)*256 + c];
  int wave = c>>6, lane = c&63;
  float s1 = v;
  s1 += __shfl_xor(s1,1); s1 += __shfl_xor(s1,2); s1 += __shfl_xor(s1,4);
  s1 += __shfl_xor(s1,8); s1 += __shfl_xor(s1,16); s1 += __shfl_xor(s1,32);
  if (lane==0) red[wave] = s1;
  __syncthreads();
  float mu = (red[0]+red[1]+red[2]+red[3]) * (1.0f/256.0f);
  float d = v - mu;
  float s2 = d*d;
  s2 += __shfl_xor(s2,1); s2 += __shfl_xor(s2,2); s2 += __shfl_xor(s2,4);
  s2 += __shfl_xor(s2,8); s2 += __shfl_xor(s2,16); s2 += __shfl_xor(s2,32);
  if (lane==0) red[4+wave] = s2;
  __syncthreads();
  float var = (red[4]+red[5]+red[6]+red[7]) * (1.0f/256.0f);
  float y = d * rsqrtf(var + 1e-5f) * g[c] + bb[c];
  float ge = 0.5f * y * (1.0f + erff(y * 0.70710678118654752f));
  out[((size_t)b*M + m)*256 + c] = f2b(ge);
}

// ---------------- fused red+ln ---------------------------------------------
__global__ __launch_bounds__(256) void red_ln_kernel(
    const float* __restrict__ x1part, const float* __restrict__ x2part,
    const float* __restrict__ sr1b, const float* __restrict__ sr2b,
    const float* __restrict__ ln1g, const float* __restrict__ ln1b,
    const float* __restrict__ ln2g, const float* __restrict__ ln2b,
    unsigned short* __restrict__ x1g, unsigned short* __restrict__ x2g,
    const float* __restrict__ ctxpart, const float* __restrict__ s_k,
    unsigned short* __restrict__ ctxcomb)
{
  __shared__ float red[8];
  if (blockIdx.x < 1568){
    lngelu_body(x1part, sr1b, ln1g, ln1b, x1g, 49, 16, 1568, blockIdx.x, red);
  } else if (blockIdx.x < 7840){
    lngelu_body(x2part, sr2b, ln2g, ln2b, x2g, 196, 4, 6272, blockIdx.x-1568, red);
  } else {
    int e = ((blockIdx.x-7840)*256 + threadIdx.x)*4;
    int b = e >> 16; int rem = e & 65535; int kg = rem >> 8; int col = rem & 255;
    float4 s = {0.f,0.f,0.f,0.f};
#pragma unroll
    for (int sk=0; sk<7; sk++){
      float4 p = *(const float4*)(ctxpart + ((((size_t)sk*B_ + b)*256 + kg)<<8) + col);
      s.x += p.x; s.y += p.y; s.z += p.z; s.w += p.w;
    }
    float inv = 1.0f / s_k[b*256 + kg];
    unsigned short pk[4] = {f2b(s.x*inv), f2b(s.y*inv), f2b(s.z*inv), f2b(s.w*inv)};
    *(uint2*)(ctxcomb + ((size_t)b*256 + kg)*512 + col) = *(uint2*)&pk[0];
  }
}

// ---------------- gmat -----------------------------------------------------
__global__ __launch_bounds__(256,2) void gmat_kernel(
    const unsigned short* __restrict__ Acomb, const unsigned short* __restrict__ ctxcomb,
    unsigned short* __restrict__ outg)
{
  __shared__ __align__(16) char smem[32768];
  char* At = smem; char* Bt = smem + 16384;
  const int b = blockIdx.x, mt = blockIdx.y, nt = blockIdx.z;
  const int t = threadIdx.x;
  const int wave = t>>6, lane = t&63, l15 = lane&15, l4 = lane>>4;
  const int wm = (wave>>1)*64, wn = (wave&1)*64;
  const unsigned short* A  = Acomb + (size_t)mt*128*512;
  const unsigned short* Bv = ctxcomb + ((size_t)b*256 + nt*128)*512;
  const f32x4 vzero = {0.f,0.f,0.f,0.f};
  f32x4 acc[4][4];
#pragma unroll
  for (int i=0;i<4;i++)
#pragma unroll
    for (int j=0;j<4;j++) acc[i][j] = vzero;

  for (int it=0; it<8; it++){
    const int k0 = it*64;
#pragma unroll
    for (int j=0;j<4;j++){
      int chunk = j*256 + t; int row = chunk>>3, c8 = chunk&7;
      int c8s = c8 ^ (row&7);
      gld16(At + (j*256 + wave*64)*16, A + (size_t)row*512 + k0 + c8s*8);
    }
#pragma unroll
    for (int j=0;j<4;j++){
      int chunk = j*256 + t; int row = chunk>>3, c8 = chunk&7;
      int c8s = c8 ^ (row&7);
      gld16(Bt + (j*256 + wave*64)*16, Bv + (size_t)row*512 + k0 + c8s*8);
    }
    __syncthreads();
#pragma unroll
    for (int ks=0;ks<2;ks++){
      short8 af[4], bfr[4];
#pragma unroll
      for (int mi=0;mi<4;mi++) af[mi]  = ldfrag(At, wm + mi*16 + l15, ks*32 + l4*8);
#pragma unroll
      for (int ni=0;ni<4;ni++) bfr[ni] = ldfrag(Bt, wn + ni*16 + l15, ks*32 + l4*8);
#pragma unroll
      for (int mi=0;mi<4;mi++)
#pragma unroll
        for (int ni=0;ni<4;ni++)
          acc[mi][ni] = mfma16(af[mi], bfr[ni], acc[mi][ni]);
    }
    __syncthreads();
  }
#pragma unroll
  for (int mi=0;mi<4;mi++)
#pragma unroll
    for (int r=0;r<4;r++){
      int og = mt*128 + wm + mi*16 + l4*4 + r;
#pragma unroll
      for (int ni=0;ni<4;ni++)
        outg[(size_t)b*65536 + (size_t)og*256 + nt*128 + wn + ni*16 + l15] = f2b(acc[mi][ni][r]);
    }
}

// ---------------- kv gemm, split-N: 246 blocks -----------------------------
__global__ __launch_bounds__(256,4) void kv_both_kernel(
    const unsigned short* __restrict__ x1g, const unsigned short* __restrict__ Wkv1T,
    const float* __restrict__ bkv1, float* __restrict__ kexp1, float* __restrict__ vraw1,
    const unsigned short* __restrict__ x2g, const unsigned short* __restrict__ Wkv2T,
    const float* __restrict__ bkv2, float* __restrict__ kexp2, float* __restrict__ vraw2)
{
  __shared__ __align__(16) char smem[8192 + 16384];
  char* At = smem; char* Bt = smem + 8192;
  const int half = blockIdx.x & 1;
  int bid = blockIdx.x >> 1;
  const unsigned short* A; const unsigned short* BT; const float* bias;
  float* kexp; float* vraw; int r0; int R;
  if (bid < 25){ A=x1g; BT=Wkv1T; bias=bkv1; kexp=kexp1; vraw=vraw1; r0=bid*64; R=1568; }
  else { A=x2g; BT=Wkv2T; bias=bkv2; kexp=kexp2; vraw=vraw2; r0=(bid-25)*64; R=6272; }
  const int t = threadIdx.x, wave = t>>6, lane = t&63, l15 = lane&15, l4 = lane>>4;
  const int wn = wave*32;
  const f32x4 vzero = {0.f,0.f,0.f,0.f};
  f32x4 acc[4][2];
#pragma unroll
  for (int i=0;i<4;i++){ acc[i][0] = vzero; acc[i][1] = vzero; }

  for (int k0 = 0; k0 < 256; k0 += 64) {
#pragma unroll
    for (int j = 0; j < 2; j++){
      int chunk = j*256 + t;
      int row = chunk >> 3, c8 = chunk & 7;
      int c8s = c8 ^ (row&7);
      int rg = r0 + row; if (rg > R-1) rg = R-1;
      gld16(At + (j*256 + wave*64)*16, A + (size_t)rg*256 + k0 + c8s*8);
    }
#pragma unroll
    for (int j = 0; j < 4; j++){
      int chunk = j*256 + t;
      int row = chunk >> 3, c8 = chunk & 7;
      int c8s = c8 ^ (row&7);
      gld16(Bt + (j*256 + wave*64)*16, BT + (size_t)(half*128 + row)*256 + k0 + c8s*8);
    }
    __syncthreads();
#pragma unroll
    for (int ks = 0; ks < 2; ks++){
      short8 af[4], bfr[2];
#pragma unroll
      for (int mi=0;mi<4;mi++) af[mi]  = ldfrag(At, mi*16 + l15, ks*32 + l4*8);
#pragma unroll
      for (int ni=0;ni<2;ni++) bfr[ni] = ldfrag(Bt, wn + ni*16 + l15, ks*32 + l4*8);
#pragma unroll
      for (int mi=0;mi<4;mi++)
#pragma unroll
        for (int ni=0;ni<2;ni++)
          acc[mi][ni] = mfma16(af[mi], bfr[ni], acc[mi][ni]);
    }
    __syncthreads();
  }
  float bb2[2];
#pragma unroll
  for (int ni=0;ni<2;ni++) bb2[ni] = bias[half*128 + wn + ni*16 + l15];
#pragma unroll
  for (int mi=0;mi<4;mi++)
#pragma unroll
    for (int ni=0;ni<2;ni++)
#pragma unroll
      for (int r=0;r<4;r++){
        int rg = r0 + mi*16 + l4*4 + r;
        if (rg < R){
          int col = wn + ni*16 + l15;
          float v = acc[mi][ni][r] + bb2[ni];
          if (half == 0) kexp[(size_t)rg*128 + col] = __expf(v);
          else           vraw[(size_t)rg*128 + col] = v;
        }
      }
}

// ---------------- dwconv (both) --------------------------------------------
__device__ __forceinline__ void dwconv_body(
    const float* __restrict__ vraw, const float* __restrict__ lcw,
    const float* __restrict__ lcb, float* __restrict__ vmod, int M, int OW, int idx)
{
  int ch = idx & 127; int rest = idx >> 7; int m = rest % M; int b = rest / M;
  if (b >= B_) return;
  int py = m / OW, px = m - py*OW;
  float acc = vraw[((size_t)b*M + m)*128 + ch] + lcb[ch];
#pragma unroll
  for (int dy=0;dy<3;dy++)
#pragma unroll
    for (int dx=0;dx<3;dx++){
      int yy = py+dy-1, xx = px+dx-1;
      if (yy>=0 && yy<OW && xx>=0 && xx<OW)
        acc += vraw[((size_t)b*M + yy*OW+xx)*128 + ch] * lcw[ch*9 + dy*3 + dx];
    }
  vmod[((size_t)b*M + m)*128 + ch] = acc;
}

__global__ __launch_bounds__(256) void dwconv_both_kernel(
    const float* __restrict__ vraw1, const float* __restrict__ lc1w,
    const float* __restrict__ lc1b, float* __restrict__ vmod1,
    const float* __restrict__ vraw2, const float* __restrict__ lc2w,
    const float* __restrict__ lc2b, float* __restrict__ vmod2)
{
  int gid = blockIdx.x*256 + threadIdx.x;
  if (blockIdx.x < 784) dwconv_body(vraw1, lc1w, lc1b, vmod1, 49, 7, gid);
  else dwconv_body(vraw2, lc2w, lc2b, vmod2, 196, 14, gid - 784*256);
}

// ---------------- branch ctx (both) ----------------------------------------
__global__ __launch_bounds__(512) void ctxbr_both_kernel(
    const float* __restrict__ kexp1, const float* __restrict__ vmod1,
    const float* __restrict__ kexp2, const float* __restrict__ vmod2,
    unsigned short* __restrict__ ctxcomb)
{
  const int b = blockIdx.x;
  int kc = blockIdx.y;
  const float* kexp; const float* vmod; int M, BR;
  if (kc < 32){ kexp = kexp1; vmod = vmod1; M = 49; BR = 0; }
  else { kexp = kexp2; vmod = vmod2; M = 196; BR = 1; kc -= 32; }
  const int t = threadIdx.x;
  const int kl = t >> 7, j = t & 127;
  const int kk = kc*4 + kl;
  const float* kp = kexp + (size_t)b*M*128 + kk;
  const float* vp = vmod + (size_t)b*M*128 + j;
  float acc = 0.f, s = 0.f;
  for (int m = 0; m < M; m++){
    float kv = kp[(size_t)m*128];
    s += kv;
    acc += kv * vp[(size_t)m*128];
  }
  const int krow = BR ? (128+kk) : kk;
  unsigned short* dst = ctxcomb + ((size_t)b*256 + krow)*512;
  const int wbase = BR ? 384 : 256;
  const int zbase = BR ? 256 : 384;
  dst[wbase + j] = f2b(acc / s);
  dst[zbase + j] = 0;
}

// ---------------- final ----------------------------------------------------
__global__ __launch_bounds__(256,4) void final_kernel(
    const unsigned short* __restrict__ Gmat, const unsigned short* __restrict__ qbuf,
    const float* __restrict__ bias_out, const float* __restrict__ s_q,
    float* __restrict__ out)
{
  __shared__ __align__(16) char smem[16384 + 8192];
  char* At = smem; char* Bt = smem + 16384;
  const int b = blockIdx.x, ot = blockIdx.y, nt = blockIdx.z;
  const int t = threadIdx.x, wave = t>>6, lane = t&63, l15 = lane&15, l4 = lane>>4;
  const int wm = (wave>>1)*64, wn = (wave&1)*32;
  const unsigned short* A  = Gmat + ((size_t)b*256 + ot*128)*256;
  const unsigned short* Bq = qbuf + ((size_t)b*N_ + nt*64)*256;
  const f32x4 vzero = {0.f,0.f,0.f,0.f};
  f32x4 acc[4][2];
#pragma unroll
  for (int i=0;i<4;i++){ acc[i][0] = vzero; acc[i][1] = vzero; }

  for (int k0=0;k0<256;k0+=64){
#pragma unroll
    for (int j=0;j<4;j++){
      int chunk = j*256 + t; int row = chunk>>3, c8 = chunk&7;
      int c8s = c8 ^ (row&7);
      gld16(At + (j*256 + wave*64)*16, A + (size_t)row*256 + k0 + c8s*8);
    }
#pragma unroll
    for (int j=0;j<2;j++){
      int chunk = j*256 + t; int row = chunk>>3, c8 = chunk&7;
      int c8s = c8 ^ (row&7);
      gld16(Bt + (j*256 + wave*64)*16, Bq + (size_t)row*256 + k0 + c8s*8);
    }
    __syncthreads();
#pragma unroll
    for (int ks=0;ks<2;ks++){
      short8 af[4], bfr[2];
#pragma unroll
      for (int mi=0;mi<4;mi++) af[mi]  = ldfrag(At, wm + mi*16 + l15, ks*32 + l4*8);
#pragma unroll
      for (int ni=0;ni<2;ni++) bfr[ni] = ldfrag(Bt, wn + ni*16 + l15, ks*32 + l4*8);
#pragma unroll
      for (int mi=0;mi<4;mi++)
#pragma unroll
        for (int ni=0;ni<2;ni++)
          acc[mi][ni] = mfma16(af[mi], bfr[ni], acc[mi][ni]);
    }
    __syncthreads();
  }
  float iq[2];
#pragma unroll
  for (int ni=0;ni<2;ni++)
    iq[ni] = 1.0f / s_q[(size_t)b*N_ + nt*64 + wn + ni*16 + l15];
#pragma unroll
  for (int mi=0;mi<4;mi++)
#pragma unroll
    for (int r=0;r<4;r++){
      int o = ot*128 + wm + mi*16 + l4*4 + r;
      float bo = bias_out[o];
#pragma unroll
      for (int ni=0;ni<2;ni++){
        int n = nt*64 + wn + ni*16 + l15;
        out[((size_t)b*256 + o)*N_ + n] = acc[mi][ni][r]*iq[ni] + bo;
      }
    }
}

// ---------------- launch ---------------------------------------------------
extern "C" void kernel_launch(void* const* d_in, const int* in_sizes, int n_in,
                              void* d_out, int out_size, void* d_ws, size_t ws_size,
                              hipStream_t stream)
{
  const float* x     = (const float*)d_in[0];
  const float* Wq    = (const float*)d_in[1];
  const float* bq    = (const float*)d_in[2];
  const float* Wk    = (const float*)d_in[3];
  const float* bk    = (const float*)d_in[4];
  const float* Wv    = (const float*)d_in[5];
  const float* bv    = (const float*)d_in[6];
  const float* sr1w  = (const float*)d_in[7];
  const float* sr1b  = (const float*)d_in[8];
  const float* ln1g  = (const float*)d_in[9];
  const float* ln1b  = (const float*)d_in[10];
  const float* sr2w  = (const float*)d_in[11];
  const float* sr2b  = (const float*)d_in[12];
  const float* ln2g  = (const float*)d_in[13];
  const float* ln2b  = (const float*)d_in[14];
  const float* Wkv1  = (const float*)d_in[15];
  const float* bkv1  = (const float*)d_in[16];
  const float* Wkv2  = (const float*)d_in[17];
  const float* bkv2  = (const float*)d_in[18];
  const float* lc1w  = (const float*)d_in[19];
  const float* lc1b  = (const float*)d_in[20];
  const float* lc2w  = (const float*)d_in[21];
  const float* lc2b  = (const float*)d_in[22];
  const float* rpw   = (const float*)d_in[23];
  const float* rpb   = (const float*)d_in[24];
  const float* rp12w = (const float*)d_in[25];
  const float* rp12b = (const float*)d_in[26];
  const float* dww   = (const float*)d_in[27];

  char* ws = (char*)d_ws;
  size_t off = 0;
  auto take = [&](size_t n)->char*{ char* p = ws + off; off += (n + 255) & ~(size_t)255; return p; };

  unsigned short* WqT   = (unsigned short*)take(131072);
  unsigned short* WkT   = (unsigned short*)take(131072);
  unsigned short* WvT   = (unsigned short*)take(131072);
  unsigned short* Wkv1T = (unsigned short*)take(131072);
  unsigned short* Wkv2T = (unsigned short*)take(131072);
  unsigned short* srw1  = (unsigned short*)take(8388608);
  unsigned short* srw2  = (unsigned short*)take(2097152);
  unsigned short* Acomb = (unsigned short*)take(262144);
  float* bias_out = (float*)take(1024);
  float* s_k      = (float*)take(32768);
  float* s_q      = (float*)take(401408);
  char* regionA = take(51380224);   // xt
  unsigned short* qbuf = (unsigned short*)take(51380224);
  char* regionK = take(51380224);   // KexpT
  char* regionV = take(51380224);   // VT -> reused after ctxmain
  float* x1part = (float*)take(25690112);
  if (off > ws_size) return;

  unsigned short* xt    = (unsigned short*)regionA;
  unsigned short* KexpT = (unsigned short*)regionK;
  unsigned short* VT = (unsigned short*)regionV;
  unsigned short* Gmat = (unsigned short*)regionV;
  unsigned short* x1g  = (unsigned short*)(regionV + 4194304);
  unsigned short* x2g  = (unsigned short*)(regionV + 4997120);
  float* kexp1 = (float*)(regionV + 8208384);
  float* vraw1 = (float*)(regionV + 9011200);
  float* vmod1 = (float*)(regionV + 9814016);
  float* kexp2 = (float*)(regionV + 10616832);
  float* vraw2 = (float*)(regionV + 13828096);
  float* vmod2 = (float*)(regionV + 17039360);
  unsigned short* ctxcomb = (unsigned short*)d_out;                 // 8.4 MB
  float* ctxpart = (float*)((char*)d_out + 8388608);                // 58.7 MB
  float* x2part  = (float*)((char*)d_out + 67108864);               // 25.7 MB

  hipMemsetAsync(s_k, 0, 32768, stream);
  prep_trans_kernel<<<8320, 256, 0, stream>>>(x, xt,
                                              Wq, Wk, Wv, Wkv1, Wkv2, sr1w, sr2w,
                                              rpw, rpb, rp12w, rp12b, dww,
                                              WqT, WkT, WvT, Wkv1T, Wkv2T, srw1, srw2,
                                              Acomb, bias_out);
  qkv_conv_kernel<<<2376, 256, 0, stream>>>(xt, WqT, WkT, WvT, bq, bk, bv,
                                            qbuf, KexpT, VT, s_q, s_k,
                                            srw1, srw2, x1part, x2part);
  ctxmain_kernel<<<896, 256, 0, stream>>>(KexpT, VT, ctxpart);
  red_ln_kernel<<<7840+2048, 256, 0, stream>>>(x1part, x2part, sr1b, sr2b,
                                               ln1g, ln1b, ln2g, ln2b, x1g, x2g,
                                               ctxpart, s_k, ctxcomb);
  kv_both_kernel<<<246, 256, 0, stream>>>(x1g, Wkv1T, bkv1, kexp1, vraw1,
                                          x2g, Wkv2T, bkv2, kexp2, vraw2);
  dwconv_both_kernel<<<3920, 256, 0, stream>>>(vraw1, lc1w, lc1b, vmod1,
                                               vraw2, lc2w, lc2b, vmod2);
  ctxbr_both_kernel<<<dim3(32,64), 512, 0, stream>>>(kexp1, vmod1, kexp2, vmod2, ctxcomb);
  gmat_kernel<<<dim3(32,2,2), 256, 0, stream>>>(Acomb, ctxcomb, Gmat);
  final_kernel<<<dim3(32,2,49), 256, 0, stream>>>(Gmat, qbuf, bias_out, s_q, (float*)d_out);
}

// Round 20
// 400.879 us; speedup vs baseline: 1.0172x; 1.0172x over previous
//
#include <hip/hip_runtime.h>
#include <hip/hip_bf16.h>
#include <math.h>

#define B_ 32
#define H_ 56
#define W_ 56
#define N_ 3136
#define NT_ 100352

typedef short short8 __attribute__((ext_vector_type(8)));
typedef float f32x4 __attribute__((ext_vector_type(4)));

__device__ __forceinline__ unsigned short f2b(float f){
  union { float f; unsigned u; } v; v.f = f;
  return (unsigned short)((v.u + 0x7FFFu + ((v.u>>16)&1u)) >> 16);
}

#define LDSW(row, bo) ((unsigned)((row)*128 + ((bo) ^ (((row)&7)<<4))))

__device__ __forceinline__ short8 ldfrag(const char* base, int row, int kk){
  return *(const short8*)(base + LDSW(row, kk*2));
}
__device__ __forceinline__ f32x4 mfma16(short8 a, short8 b, f32x4 c){
  return __builtin_amdgcn_mfma_f32_16x16x32_bf16(a, b, c, 0, 0, 0);
}
__device__ __forceinline__ void gld16(void* lds, const void* g){
  __builtin_amdgcn_global_load_lds((__attribute__((address_space(1))) void*)g,
                                   (__attribute__((address_space(3))) void*)lds,
                                   16, 0, 0);
}

// ---------------- fused prep + transpose -----------------------------------
__global__ void prep_trans_kernel(
    const float* __restrict__ x, unsigned short* __restrict__ xt,
    const float* __restrict__ Wq, const float* __restrict__ Wk,
    const float* __restrict__ Wv, const float* __restrict__ Wkv1,
    const float* __restrict__ Wkv2, const float* __restrict__ sr1w,
    const float* __restrict__ sr2w, const float* __restrict__ rpw,
    const float* __restrict__ rpb, const float* __restrict__ rp12w,
    const float* __restrict__ rp12b, const float* __restrict__ dww,
    unsigned short* WqT, unsigned short* WkT, unsigned short* WvT,
    unsigned short* Wkv1T, unsigned short* Wkv2T,
    unsigned short* srw1, unsigned short* srw2,
    unsigned short* Acomb, float* bias_out)
{
  __shared__ float tile[64][65];
  if (blockIdx.x < 6272){
    int bn = blockIdx.x >> 2; int b = bn / 49; int n0 = (bn - b*49)*64;
    int c0 = (blockIdx.x & 3)*64;
    int t = threadIdx.x;
    {
      int cl = t >> 2, nq = t & 3;
      const float* src = x + ((size_t)(b*256 + c0 + cl))*N_ + n0 + nq*16;
#pragma unroll
      for (int j = 0; j < 4; j++){
        float4 v = *(const float4*)(src + j*4);
        tile[cl][nq*16 + j*4 + 0] = v.x;
        tile[cl][nq*16 + j*4 + 1] = v.y;
        tile[cl][nq*16 + j*4 + 2] = v.z;
        tile[cl][nq*16 + j*4 + 3] = v.w;
      }
    }
    __syncthreads();
    {
      int nl = t >> 2, cq = t & 3;
      unsigned short pk[16];
#pragma unroll
      for (int j=0;j<16;j++) pk[j] = f2b(tile[cq*16+j][nl]);
      unsigned short* dst = xt + ((size_t)(b*N_ + n0 + nl))*256 + c0 + cq*16;
      *(uint4*)dst = *(uint4*)&pk[0];
      *(uint4*)(dst+8) = *(uint4*)&pk[8];
    }
    return;
  }
  int idx = (blockIdx.x - 6272)*256 + threadIdx.x;
  const int stride = 2048*256;
  const int total = 5*65536 + 4194304 + 1048576 + 131072 + 256;
  for (int i = idx; i < total; i += stride) {
    int j = i;
    if (j < 5*65536) {
      int w = j >> 16, e = j & 65535;
      int o = e >> 8, c = e & 255;
      const float* src = (w==0)?Wq:(w==1)?Wk:(w==2)?Wv:(w==3)?Wkv1:Wkv2;
      unsigned short* dst = (w==0)?WqT:(w==1)?WkT:(w==2)?WvT:(w==3)?Wkv1T:Wkv2T;
      dst[o*256+c] = f2b(src[c*256+o]);
      continue;
    }
    j -= 5*65536;
    if (j < 4194304) {
      int o = j >> 14, rem = j & 16383, pos = rem >> 8, c = rem & 255;
      srw1[j] = f2b(sr1w[o*16384 + c*64 + pos]);
      continue;
    }
    j -= 4194304;
    if (j < 1048576) {
      int o = j >> 12, rem = j & 4095, pos = rem >> 8, c = rem & 255;
      srw2[j] = f2b(sr2w[o*4096 + c*16 + pos]);
      continue;
    }
    j -= 1048576;
    if (j < 131072) {
      int o = j >> 9, i2 = j & 511;
      float v = (i2 < 256) ? dww[o*2+0]*rpw[o*256+i2]
                           : dww[o*2+1]*rp12w[o*256+(i2-256)];
      Acomb[o*512+i2] = f2b(v);
      continue;
    }
    j -= 131072;
    bias_out[j] = dww[j*2+0]*rpb[j] + dww[j*2+1]*rp12b[j];
  }
}

// ---------------- qkv3 (best measured: A resident, B full, min barriers) ---
__global__ __launch_bounds__(256,2) void qkv3_kernel(
    const unsigned short* __restrict__ xt,
    const unsigned short* __restrict__ WqT, const unsigned short* __restrict__ WkT,
    const unsigned short* __restrict__ WvT,
    const float* __restrict__ bq, const float* __restrict__ bk, const float* __restrict__ bv,
    unsigned short* __restrict__ qbuf, unsigned short* __restrict__ KexpT,
    unsigned short* __restrict__ VT, float* __restrict__ s_q, float* __restrict__ s_k)
{
  __shared__ __align__(16) char smem[32768 + 32768 + 1024];
  char* At = smem;
  char* Bt = smem + 32768;
  float* redbuf = (float*)(smem + 65536);
  const int t = threadIdx.x, wave = t>>6, lane = t&63, l15 = lane&15, l4 = lane>>4;
  const int r0 = blockIdx.x*64;
  const int b = r0 / N_;
  const int nl0 = r0 - b*N_;

#pragma unroll
  for (int c4=0;c4<4;c4++)
#pragma unroll
    for (int j=0;j<2;j++){
      int chunk = j*256 + t; int row = chunk>>3, c8 = chunk&7;
      int c8s = c8 ^ (row&7);
      gld16(At + c4*8192 + (j*256 + wave*64)*16,
            xt + (size_t)(r0+row)*256 + c4*64 + c8s*8);
    }
  __syncthreads();

  for (int mat=0; mat<3; mat++){
    const unsigned short* BT = (mat==0)?WqT:(mat==1)?WkT:WvT;
    const float* bias = (mat==0)?bq:(mat==1)?bk:bv;
    const f32x4 vzero = {0.f,0.f,0.f,0.f};
    f32x4 acc[4][4];
#pragma unroll
    for (int i=0;i<4;i++)
#pragma unroll
      for (int j=0;j<4;j++) acc[i][j] = vzero;

    for (int k0c=0;k0c<4;k0c++){
#pragma unroll
      for (int j=0;j<8;j++){
        int chunk = j*256 + t; int row = chunk>>3, c8 = chunk&7;
        int c8s = c8 ^ (row&7);
        gld16(Bt + (j*256 + wave*64)*16, BT + (size_t)row*256 + k0c*64 + c8s*8);
      }
      __syncthreads();
#pragma unroll
      for (int ks=0;ks<2;ks++){
        short8 af[4], bfr[4];
#pragma unroll
        for (int mi=0;mi<4;mi++) af[mi]  = ldfrag(At + k0c*8192, mi*16 + l15, ks*32 + l4*8);
#pragma unroll
        for (int ni=0;ni<4;ni++) bfr[ni] = ldfrag(Bt, wave*64 + ni*16 + l15, ks*32 + l4*8);
#pragma unroll
        for (int mi=0;mi<4;mi++)
#pragma unroll
          for (int ni=0;ni<4;ni++)
            acc[mi][ni] = mfma16(af[mi], bfr[ni], acc[mi][ni]);
      }
      __syncthreads();
    }

    float bb4[4];
#pragma unroll
    for (int ni=0;ni<4;ni++) bb4[ni] = bias[wave*64 + ni*16 + l15];

    if (mat == 0) {
      float rs[4][4];
#pragma unroll
      for (int mi=0;mi<4;mi++)
#pragma unroll
        for (int r=0;r<4;r++) rs[mi][r] = 0.f;
#pragma unroll
      for (int mi=0;mi<4;mi++)
#pragma unroll
        for (int ni=0;ni<4;ni++)
#pragma unroll
          for (int r=0;r<4;r++){
            float e = __expf(acc[mi][ni][r] + bb4[ni]);
            acc[mi][ni][r] = e;
            rs[mi][r] += e;
          }
#pragma unroll
      for (int mi=0;mi<4;mi++)
#pragma unroll
        for (int r=0;r<4;r++){
          float s = rs[mi][r];
          s += __shfl_xor(s, 1); s += __shfl_xor(s, 2);
          s += __shfl_xor(s, 4); s += __shfl_xor(s, 8);
          rs[mi][r] = s;
        }
      if (l15 == 0){
#pragma unroll
        for (int mi=0;mi<4;mi++)
#pragma unroll
          for (int r=0;r<4;r++)
            redbuf[wave*64 + mi*16 + l4*4 + r] = rs[mi][r];
      }
      __syncthreads();
      unsigned short* qb = (unsigned short*)Bt;
#pragma unroll
      for (int mi=0;mi<4;mi++)
#pragma unroll
        for (int r=0;r<4;r++){
          int rr = mi*16 + l4*4 + r;
#pragma unroll
          for (int ni=0;ni<4;ni++)
            qb[rr*256 + wave*64 + ni*16 + l15] = f2b(acc[mi][ni][r]);
        }
      if (t < 64){
        s_q[r0 + t] = redbuf[t] + redbuf[64+t] + redbuf[128+t] + redbuf[192+t];
      }
      __syncthreads();
#pragma unroll
      for (int j=0;j<8;j++){
        int chunk = j*256 + t;
        int row = chunk >> 5, c8 = chunk & 31;
        *(uint4*)(qbuf + (size_t)(r0+row)*256 + c8*8) = *(const uint4*)(qb + row*256 + c8*8);
      }
      __syncthreads();
    } else {
      float cs[4] = {0.f,0.f,0.f,0.f};
#pragma unroll
      for (int mi=0;mi<4;mi++)
#pragma unroll
        for (int ni=0;ni<4;ni++)
#pragma unroll
          for (int r=0;r<4;r++){
            float v = acc[mi][ni][r] + bb4[ni];
            if (mat == 1){ v = __expf(v); cs[ni] += v; }
            int row = mi*16 + l4*4 + r;
            int col = wave*64 + ni*16 + l15;
            *(unsigned short*)(Bt + LDSW(col, row*2)) = f2b(v);
          }
      if (mat == 1){
#pragma unroll
        for (int ni=0;ni<4;ni++){
          float s = cs[ni];
          s += __shfl_xor(s, 16);
          s += __shfl_xor(s, 32);
          if (lane < 16) atomicAdd(&s_k[b*256 + wave*64 + ni*16 + lane], s);
        }
      }
      __syncthreads();
      unsigned short* ot = (mat==1) ? KexpT : VT;
#pragma unroll
      for (int j=0;j<8;j++){
        int chunk = j*256 + t;
        int c = chunk >> 3, n8 = chunk & 7;
        *(uint4*)(ot + ((size_t)b*256 + c)*N_ + nl0 + n8*8) = *(const uint4*)(Bt + LDSW(c, n8*16));
      }
      __syncthreads();
    }
  }
}

// ---------------- srconv body ----------------------------------------------
template<int S, int OW, int KW, int NSK, int MPB, int KTOT>
__device__ __forceinline__ void srconv_body(
    const unsigned short* __restrict__ xt, const unsigned short* __restrict__ wbf,
    float* __restrict__ part, int bid, char* At, char* Bt)
{
  const int KCH = KTOT / NSK;
  const int Mtot = B_*MPB;
  const int sk = bid % NSK, tile = bid / NSK;
  const int t = threadIdx.x, wave = t>>6, lane = t&63, l15 = lane&15, l4 = lane>>4;
  const f32x4 vzero = {0.f,0.f,0.f,0.f};
  f32x4 acc[4][4];
#pragma unroll
  for (int i=0;i<4;i++)
#pragma unroll
    for (int j=0;j<4;j++) acc[i][j] = vzero;

  size_t abase[2];
#pragma unroll
  for (int j=0;j<2;j++){
    int chunk = j*256 + t;
    int row = chunk >> 3, c8 = chunk & 7;
    int c8s = c8 ^ (row&7);
    int rowc = tile*64 + row; if (rowc > Mtot-1) rowc = Mtot-1;
    int b = rowc / MPB; int m = rowc - b*MPB;
    int p = m / OW; int q = m - p*OW;
    abase[j] = ((size_t)b*N_ + (size_t)(S*p)*W_ + S*q)*256 + c8s*8;
  }

  for (int kt = 0; kt < KCH; kt += 64){
    const int k0 = sk*KCH + kt;
    const int pos = k0 >> 8, cc = k0 & 255;
    const int dy = pos / KW, dx = pos - dy*KW;
    const size_t off = (size_t)(dy*W_ + dx)*256 + cc;
#pragma unroll
    for (int j=0;j<2;j++){
      gld16(At + (j*256 + wave*64)*16, xt + abase[j] + off);
    }
#pragma unroll
    for (int j=0;j<8;j++){
      int chunk = j*256 + t; int row = chunk>>3, c8 = chunk&7;
      int c8s = c8 ^ (row&7);
      gld16(Bt + (j*256 + wave*64)*16, wbf + (size_t)row*KTOT + k0 + c8s*8);
    }
    __syncthreads();
#pragma unroll
    for (int ks=0;ks<2;ks++){
      short8 af[4], bfr[4];
#pragma unroll
      for (int mi=0;mi<4;mi++) af[mi]  = ldfrag(At, mi*16 + l15, ks*32 + l4*8);
#pragma unroll
      for (int ni=0;ni<4;ni++) bfr[ni] = ldfrag(Bt, wave*64 + ni*16 + l15, ks*32 + l4*8);
#pragma unroll
      for (int mi=0;mi<4;mi++)
#pragma unroll
        for (int ni=0;ni<4;ni++)
          acc[mi][ni] = mfma16(af[mi], bfr[ni], acc[mi][ni]);
    }
    __syncthreads();
  }
#pragma unroll
  for (int mi=0;mi<4;mi++)
#pragma unroll
    for (int r=0;r<4;r++){
      int row = tile*64 + mi*16 + l4*4 + r;
      if (row < Mtot){
        size_t basep = ((size_t)sk*Mtot + row)*256;
#pragma unroll
        for (int ni=0;ni<4;ni++)
          part[basep + wave*64 + ni*16 + l15] = acc[mi][ni][r];
      }
    }
}

// ---------------- ctx main body (split-K 7, XCD-local (b,sk) groups) -------
__device__ __forceinline__ void ctxmain_body(
    const unsigned short* __restrict__ KexpT, const unsigned short* __restrict__ VT,
    float* __restrict__ part, int orig, char* At, char* Bt)
{
  const int idx = (orig & 7)*112 + (orig >> 3);
  const int b = idx / 28; int rem = idx - b*28;
  const int sk = rem >> 2, y = rem & 3;
  const int mt = y >> 1, nt = y & 1;
  const int it0 = sk*7, it1 = it0+7;
  const int t = threadIdx.x;
  const int wave = t>>6, lane = t&63, l15 = lane&15, l4 = lane>>4;
  const int wm = (wave>>1)*64, wn = (wave&1)*64;
  const unsigned short* A  = KexpT + ((size_t)b*256 + mt*128)*N_;
  const unsigned short* Bv = VT + ((size_t)b*256 + nt*128)*N_;
  const f32x4 vzero = {0.f,0.f,0.f,0.f};
  f32x4 acc[4][4];
#pragma unroll
  for (int i=0;i<4;i++)
#pragma unroll
    for (int j=0;j<4;j++) acc[i][j] = vzero;

  for (int it=it0; it<it1; it++){
    const int k0 = it*64;
#pragma unroll
    for (int j=0;j<4;j++){
      int chunk = j*256 + t; int row = chunk>>3, c8 = chunk&7;
      int c8s = c8 ^ (row&7);
      gld16(At + (j*256 + wave*64)*16, A + (size_t)row*N_ + k0 + c8s*8);
    }
#pragma unroll
    for (int j=0;j<4;j++){
      int chunk = j*256 + t; int row = chunk>>3, c8 = chunk&7;
      int c8s = c8 ^ (row&7);
      gld16(Bt + (j*256 + wave*64)*16, Bv + (size_t)row*N_ + k0 + c8s*8);
    }
    __syncthreads();
#pragma unroll
    for (int ks=0;ks<2;ks++){
      short8 af[4], bfr[4];
#pragma unroll
      for (int mi=0;mi<4;mi++) af[mi]  = ldfrag(At, wm + mi*16 + l15, ks*32 + l4*8);
#pragma unroll
      for (int ni=0;ni<4;ni++) bfr[ni] = ldfrag(Bt, wn + ni*16 + l15, ks*32 + l4*8);
#pragma unroll
      for (int mi=0;mi<4;mi++)
#pragma unroll
        for (int ni=0;ni<4;ni++)
          acc[mi][ni] = mfma16(af[mi], bfr[ni], acc[mi][ni]);
    }
    __syncthreads();
  }
#pragma unroll
  for (int mi=0;mi<4;mi++)
#pragma unroll
    for (int r=0;r<4;r++){
      int kg = mt*128 + wm + mi*16 + l4*4 + r;
      size_t basep = (((size_t)sk*B_ + b)*256 + kg)*256 + nt*128 + wn;
#pragma unroll
      for (int ni=0;ni<4;ni++)
        part[basep + ni*16 + l15] = acc[mi][ni][r];
    }
}

// ---------------- fused conv+ctx -------------------------------------------
__global__ __launch_bounds__(256,4) void conv_ctx_kernel(
    const unsigned short* __restrict__ xt, const unsigned short* __restrict__ srw1,
    const unsigned short* __restrict__ srw2, float* __restrict__ x1part,
    float* __restrict__ x2part, const unsigned short* __restrict__ KexpT,
    const unsigned short* __restrict__ VT, float* __restrict__ ctxpart)
{
  __shared__ __align__(16) char smem[8192 + 32768];
  if (blockIdx.x < 392)
    srconv_body<4,14,4,4,196,4096>(xt, srw2, x2part, blockIdx.x, smem, smem+8192);
  else if (blockIdx.x < 792)
    srconv_body<8,7,8,16,49,16384>(xt, srw1, x1part, blockIdx.x-392, smem, smem+8192);
  else
    ctxmain_body(KexpT, VT, ctxpart, blockIdx.x-792, smem, smem+16384);
}

// ---------------- LN+GELU body ---------------------------------------------
__device__ __forceinline__ void lngelu_body(
    const float* __restrict__ part, const float* __restrict__ srb,
    const float* __restrict__ g, const float* __restrict__ bb,
    unsigned short* __restrict__ out, int M, int nsk, int Mtot, int bid,
    float* red)
{
  int b = bid / M, m = bid - b*M;
  int c = threadIdx.x;
  float v = srb[c];
  for (int s=0;s<nsk;s++) v += part[((size_t)s*Mtot + b*M + m)*256 + c];
  int wave = c>>6, lane = c&63;
  float s1 = v;
  s1 += __shfl_xor(s1,1); s1 += __shfl_xor(s1,2); s1 += __shfl_xor(s1,4);
  s1 += __shfl_xor(s1,8); s1 += __shfl_xor(s1,16); s1 += __shfl_xor(s1,32);
  if (lane==0) red[wave] = s1;
  __syncthreads();
  float mu = (red[0]+red[1]+red[2]+red[3]) * (1.0f/256.0f);
  float d = v - mu;
  float s2 = d*d;
  s2 += __shfl_xor(s2,1); s2 += __shfl_xor(s2,2); s2 += __shfl_xor(s2,4);
  s2 += __shfl_xor(s2,8); s2 += __shfl_xor(s2,16); s2 += __shfl_xor(s2,32);
  if (lane==0) red[4+wave] = s2;
  __syncthreads();
  float var = (red[4]+red[5]+red[6]+red[7]) * (1.0f/256.0f);
  float y = d * rsqrtf(var + 1e-5f) * g[c] + bb[c];
  float ge = 0.5f * y * (1.0f + erff(y * 0.70710678118654752f));
  out[((size_t)b*M + m)*256 + c] = f2b(ge);
}

// ---------------- fused red+ln ---------------------------------------------
__global__ __launch_bounds__(256) void red_ln_kernel(
    const float* __restrict__ x1part, const float* __restrict__ x2part,
    const float* __restrict__ sr1b, const float* __restrict__ sr2b,
    const float* __restrict__ ln1g, const float* __restrict__ ln1b,
    const float* __restrict__ ln2g, const float* __restrict__ ln2b,
    unsigned short* __restrict__ x1g, unsigned short* __restrict__ x2g,
    const float* __restrict__ ctxpart, const float* __restrict__ s_k,
    unsigned short* __restrict__ ctxcomb)
{
  __shared__ float red[8];
  if (blockIdx.x < 1568){
    lngelu_body(x1part, sr1b, ln1g, ln1b, x1g, 49, 16, 1568, blockIdx.x, red);
  } else if (blockIdx.x < 7840){
    lngelu_body(x2part, sr2b, ln2g, ln2b, x2g, 196, 4, 6272, blockIdx.x-1568, red);
  } else {
    int e = ((blockIdx.x-7840)*256 + threadIdx.x)*4;
    int b = e >> 16; int rem = e & 65535; int kg = rem >> 8; int col = rem & 255;
    float4 s = {0.f,0.f,0.f,0.f};
#pragma unroll
    for (int sk=0; sk<7; sk++){
      float4 p = *(const float4*)(ctxpart + ((((size_t)sk*B_ + b)*256 + kg)<<8) + col);
      s.x += p.x; s.y += p.y; s.z += p.z; s.w += p.w;
    }
    float inv = 1.0f / s_k[b*256 + kg];
    unsigned short pk[4] = {f2b(s.x*inv), f2b(s.y*inv), f2b(s.z*inv), f2b(s.w*inv)};
    *(uint2*)(ctxcomb + ((size_t)b*256 + kg)*512 + col) = *(uint2*)&pk[0];
  }
}

// ---------------- gmat -----------------------------------------------------
__global__ __launch_bounds__(256,2) void gmat_kernel(
    const unsigned short* __restrict__ Acomb, const unsigned short* __restrict__ ctxcomb,
    unsigned short* __restrict__ outg)
{
  __shared__ __align__(16) char smem[32768];
  char* At = smem; char* Bt = smem + 16384;
  const int b = blockIdx.x, mt = blockIdx.y, nt = blockIdx.z;
  const int t = threadIdx.x;
  const int wave = t>>6, lane = t&63, l15 = lane&15, l4 = lane>>4;
  const int wm = (wave>>1)*64, wn = (wave&1)*64;
  const unsigned short* A  = Acomb + (size_t)mt*128*512;
  const unsigned short* Bv = ctxcomb + ((size_t)b*256 + nt*128)*512;
  const f32x4 vzero = {0.f,0.f,0.f,0.f};
  f32x4 acc[4][4];
#pragma unroll
  for (int i=0;i<4;i++)
#pragma unroll
    for (int j=0;j<4;j++) acc[i][j] = vzero;

  for (int it=0; it<8; it++){
    const int k0 = it*64;
#pragma unroll
    for (int j=0;j<4;j++){
      int chunk = j*256 + t; int row = chunk>>3, c8 = chunk&7;
      int c8s = c8 ^ (row&7);
      gld16(At + (j*256 + wave*64)*16, A + (size_t)row*512 + k0 + c8s*8);
    }
#pragma unroll
    for (int j=0;j<4;j++){
      int chunk = j*256 + t; int row = chunk>>3, c8 = chunk&7;
      int c8s = c8 ^ (row&7);
      gld16(Bt + (j*256 + wave*64)*16, Bv + (size_t)row*512 + k0 + c8s*8);
    }
    __syncthreads();
#pragma unroll
    for (int ks=0;ks<2;ks++){
      short8 af[4], bfr[4];
#pragma unroll
      for (int mi=0;mi<4;mi++) af[mi]  = ldfrag(At, wm + mi*16 + l15, ks*32 + l4*8);
#pragma unroll
      for (int ni=0;ni<4;ni++) bfr[ni] = ldfrag(Bt, wn + ni*16 + l15, ks*32 + l4*8);
#pragma unroll
      for (int mi=0;mi<4;mi++)
#pragma unroll
        for (int ni=0;ni<4;ni++)
          acc[mi][ni] = mfma16(af[mi], bfr[ni], acc[mi][ni]);
    }
    __syncthreads();
  }
#pragma unroll
  for (int mi=0;mi<4;mi++)
#pragma unroll
    for (int r=0;r<4;r++){
      int og = mt*128 + wm + mi*16 + l4*4 + r;
#pragma unroll
      for (int ni=0;ni<4;ni++)
        outg[(size_t)b*65536 + (size_t)og*256 + nt*128 + wn + ni*16 + l15] = f2b(acc[mi][ni][r]);
    }
}

// ---------------- kv gemm, split-N: 246 blocks -----------------------------
__global__ __launch_bounds__(256,4) void kv_both_kernel(
    const unsigned short* __restrict__ x1g, const unsigned short* __restrict__ Wkv1T,
    const float* __restrict__ bkv1, float* __restrict__ kexp1, float* __restrict__ vraw1,
    const unsigned short* __restrict__ x2g, const unsigned short* __restrict__ Wkv2T,
    const float* __restrict__ bkv2, float* __restrict__ kexp2, float* __restrict__ vraw2)
{
  __shared__ __align__(16) char smem[8192 + 16384];
  char* At = smem; char* Bt = smem + 8192;
  const int half = blockIdx.x & 1;
  int bid = blockIdx.x >> 1;
  const unsigned short* A; const unsigned short* BT; const float* bias;
  float* kexp; float* vraw; int r0; int R;
  if (bid < 25){ A=x1g; BT=Wkv1T; bias=bkv1; kexp=kexp1; vraw=vraw1; r0=bid*64; R=1568; }
  else { A=x2g; BT=Wkv2T; bias=bkv2; kexp=kexp2; vraw=vraw2; r0=(bid-25)*64; R=6272; }
  const int t = threadIdx.x, wave = t>>6, lane = t&63, l15 = lane&15, l4 = lane>>4;
  const int wn = wave*32;
  const f32x4 vzero = {0.f,0.f,0.f,0.f};
  f32x4 acc[4][2];
#pragma unroll
  for (int i=0;i<4;i++){ acc[i][0] = vzero; acc[i][1] = vzero; }

  for (int k0 = 0; k0 < 256; k0 += 64) {
#pragma unroll
    for (int j = 0; j < 2; j++){
      int chunk = j*256 + t;
      int row = chunk >> 3, c8 = chunk & 7;
      int c8s = c8 ^ (row&7);
      int rg = r0 + row; if (rg > R-1) rg = R-1;
      gld16(At + (j*256 + wave*64)*16, A + (size_t)rg*256 + k0 + c8s*8);
    }
#pragma unroll
    for (int j = 0; j < 4; j++){
      int chunk = j*256 + t;
      int row = chunk >> 3, c8 = chunk & 7;
      int c8s = c8 ^ (row&7);
      gld16(Bt + (j*256 + wave*64)*16, BT + (size_t)(half*128 + row)*256 + k0 + c8s*8);
    }
    __syncthreads();
#pragma unroll
    for (int ks = 0; ks < 2; ks++){
      short8 af[4], bfr[2];
#pragma unroll
      for (int mi=0;mi<4;mi++) af[mi]  = ldfrag(At, mi*16 + l15, ks*32 + l4*8);
#pragma unroll
      for (int ni=0;ni<2;ni++) bfr[ni] = ldfrag(Bt, wn + ni*16 + l15, ks*32 + l4*8);
#pragma unroll
      for (int mi=0;mi<4;mi++)
#pragma unroll
        for (int ni=0;ni<2;ni++)
          acc[mi][ni] = mfma16(af[mi], bfr[ni], acc[mi][ni]);
    }
    __syncthreads();
  }
  float bb2[2];
#pragma unroll
  for (int ni=0;ni<2;ni++) bb2[ni] = bias[half*128 + wn + ni*16 + l15];
#pragma unroll
  for (int mi=0;mi<4;mi++)
#pragma unroll
    for (int ni=0;ni<2;ni++)
#pragma unroll
      for (int r=0;r<4;r++){
        int rg = r0 + mi*16 + l4*4 + r;
        if (rg < R){
          int col = wn + ni*16 + l15;
          float v = acc[mi][ni][r] + bb2[ni];
          if (half == 0) kexp[(size_t)rg*128 + col] = __expf(v);
          else           vraw[(size_t)rg*128 + col] = v;
        }
      }
}

// ---------------- dwconv (both) --------------------------------------------
__device__ __forceinline__ void dwconv_body(
    const float* __restrict__ vraw, const float* __restrict__ lcw,
    const float* __restrict__ lcb, float* __restrict__ vmod, int M, int OW, int idx)
{
  int ch = idx & 127; int rest = idx >> 7; int m = rest % M; int b = rest / M;
  if (b >= B_) return;
  int py = m / OW, px = m - py*OW;
  float acc = vraw[((size_t)b*M + m)*128 + ch] + lcb[ch];
#pragma unroll
  for (int dy=0;dy<3;dy++)
#pragma unroll
    for (int dx=0;dx<3;dx++){
      int yy = py+dy-1, xx = px+dx-1;
      if (yy>=0 && yy<OW && xx>=0 && xx<OW)
        acc += vraw[((size_t)b*M + yy*OW+xx)*128 + ch] * lcw[ch*9 + dy*3 + dx];
    }
  vmod[((size_t)b*M + m)*128 + ch] = acc;
}

__global__ __launch_bounds__(256) void dwconv_both_kernel(
    const float* __restrict__ vraw1, const float* __restrict__ lc1w,
    const float* __restrict__ lc1b, float* __restrict__ vmod1,
    const float* __restrict__ vraw2, const float* __restrict__ lc2w,
    const float* __restrict__ lc2b, float* __restrict__ vmod2)
{
  int gid = blockIdx.x*256 + threadIdx.x;
  if (blockIdx.x < 784) dwconv_body(vraw1, lc1w, lc1b, vmod1, 49, 7, gid);
  else dwconv_body(vraw2, lc2w, lc2b, vmod2, 196, 14, gid - 784*256);
}

// ---------------- branch ctx (both) ----------------------------------------
__global__ __launch_bounds__(512) void ctxbr_both_kernel(
    const float* __restrict__ kexp1, const float* __restrict__ vmod1,
    const float* __restrict__ kexp2, const float* __restrict__ vmod2,
    unsigned short* __restrict__ ctxcomb)
{
  const int b = blockIdx.x;
  int kc = blockIdx.y;
  const float* kexp; const float* vmod; int M, BR;
  if (kc < 32){ kexp = kexp1; vmod = vmod1; M = 49; BR = 0; }
  else { kexp = kexp2; vmod = vmod2; M = 196; BR = 1; kc -= 32; }
  const int t = threadIdx.x;
  const int kl = t >> 7, j = t & 127;
  const int kk = kc*4 + kl;
  const float* kp = kexp + (size_t)b*M*128 + kk;
  const float* vp = vmod + (size_t)b*M*128 + j;
  float acc = 0.f, s = 0.f;
  for (int m = 0; m < M; m++){
    float kv = kp[(size_t)m*128];
    s += kv;
    acc += kv * vp[(size_t)m*128];
  }
  const int krow = BR ? (128+kk) : kk;
  unsigned short* dst = ctxcomb + ((size_t)b*256 + krow)*512;
  const int wbase = BR ? 384 : 256;
  const int zbase = BR ? 256 : 384;
  dst[wbase + j] = f2b(acc / s);
  dst[zbase + j] = 0;
}

// ---------------- final ----------------------------------------------------
__global__ __launch_bounds__(256,4) void final_kernel(
    const unsigned short* __restrict__ Gmat, const unsigned short* __restrict__ qbuf,
    const float* __restrict__ bias_out, const float* __restrict__ s_q,
    float* __restrict__ out)
{
  __shared__ __align__(16) char smem[16384 + 8192];
  char* At = smem; char* Bt = smem + 16384;
  const int b = blockIdx.x, ot = blockIdx.y, nt = blockIdx.z;
  const int t = threadIdx.x, wave = t>>6, lane = t&63, l15 = lane&15, l4 = lane>>4;
  const int wm = (wave>>1)*64, wn = (wave&1)*32;
  const unsigned short* A  = Gmat + ((size_t)b*256 + ot*128)*256;
  const unsigned short* Bq = qbuf + ((size_t)b*N_ + nt*64)*256;
  const f32x4 vzero = {0.f,0.f,0.f,0.f};
  f32x4 acc[4][2];
#pragma unroll
  for (int i=0;i<4;i++){ acc[i][0] = vzero; acc[i][1] = vzero; }

  for (int k0=0;k0<256;k0+=64){
#pragma unroll
    for (int j=0;j<4;j++){
      int chunk = j*256 + t; int row = chunk>>3, c8 = chunk&7;
      int c8s = c8 ^ (row&7);
      gld16(At + (j*256 + wave*64)*16, A + (size_t)row*256 + k0 + c8s*8);
    }
#pragma unroll
    for (int j=0;j<2;j++){
      int chunk = j*256 + t; int row = chunk>>3, c8 = chunk&7;
      int c8s = c8 ^ (row&7);
      gld16(Bt + (j*256 + wave*64)*16, Bq + (size_t)row*256 + k0 + c8s*8);
    }
    __syncthreads();
#pragma unroll
    for (int ks=0;ks<2;ks++){
      short8 af[4], bfr[2];
#pragma unroll
      for (int mi=0;mi<4;mi++) af[mi]  = ldfrag(At, wm + mi*16 + l15, ks*32 + l4*8);
#pragma unroll
      for (int ni=0;ni<2;ni++) bfr[ni] = ldfrag(Bt, wn + ni*16 + l15, ks*32 + l4*8);
#pragma unroll
      for (int mi=0;mi<4;mi++)
#pragma unroll
        for (int ni=0;ni<2;ni++)
          acc[mi][ni] = mfma16(af[mi], bfr[ni], acc[mi][ni]);
    }
    __syncthreads();
  }
  float iq[2];
#pragma unroll
  for (int ni=0;ni<2;ni++)
    iq[ni] = 1.0f / s_q[(size_t)b*N_ + nt*64 + wn + ni*16 + l15];
#pragma unroll
  for (int mi=0;mi<4;mi++)
#pragma unroll
    for (int r=0;r<4;r++){
      int o = ot*128 + wm + mi*16 + l4*4 + r;
      float bo = bias_out[o];
#pragma unroll
      for (int ni=0;ni<2;ni++){
        int n = nt*64 + wn + ni*16 + l15;
        out[((size_t)b*256 + o)*N_ + n] = acc[mi][ni][r]*iq[ni] + bo;
      }
    }
}

// ---------------- launch ---------------------------------------------------
extern "C" void kernel_launch(void* const* d_in, const int* in_sizes, int n_in,
                              void* d_out, int out_size, void* d_ws, size_t ws_size,
                              hipStream_t stream)
{
  const float* x     = (const float*)d_in[0];
  const float* Wq    = (const float*)d_in[1];
  const float* bq    = (const float*)d_in[2];
  const float* Wk    = (const float*)d_in[3];
  const float* bk    = (const float*)d_in[4];
  const float* Wv    = (const float*)d_in[5];
  const float* bv    = (const float*)d_in[6];
  const float* sr1w  = (const float*)d_in[7];
  const float* sr1b  = (const float*)d_in[8];
  const float* ln1g  = (const float*)d_in[9];
  const float* ln1b  = (const float*)d_in[10];
  const float* sr2w  = (const float*)d_in[11];
  const float* sr2b  = (const float*)d_in[12];
  const float* ln2g  = (const float*)d_in[13];
  const float* ln2b  = (const float*)d_in[14];
  const float* Wkv1  = (const float*)d_in[15];
  const float* bkv1  = (const float*)d_in[16];
  const float* Wkv2  = (const float*)d_in[17];
  const float* bkv2  = (const float*)d_in[18];
  const float* lc1w  = (const float*)d_in[19];
  const float* lc1b  = (const float*)d_in[20];
  const float* lc2w  = (const float*)d_in[21];
  const float* lc2b  = (const float*)d_in[22];
  const float* rpw   = (const float*)d_in[23];
  const float* rpb   = (const float*)d_in[24];
  const float* rp12w = (const float*)d_in[25];
  const float* rp12b = (const float*)d_in[26];
  const float* dww   = (const float*)d_in[27];

  char* ws = (char*)d_ws;
  size_t off = 0;
  auto take = [&](size_t n)->char*{ char* p = ws + off; off += (n + 255) & ~(size_t)255; return p; };

  unsigned short* WqT   = (unsigned short*)take(131072);
  unsigned short* WkT   = (unsigned short*)take(131072);
  unsigned short* WvT   = (unsigned short*)take(131072);
  unsigned short* Wkv1T = (unsigned short*)take(131072);
  unsigned short* Wkv2T = (unsigned short*)take(131072);
  unsigned short* srw1  = (unsigned short*)take(8388608);
  unsigned short* srw2  = (unsigned short*)take(2097152);
  unsigned short* Acomb = (unsigned short*)take(262144);
  float* bias_out = (float*)take(1024);
  float* s_k      = (float*)take(32768);
  float* s_q      = (float*)take(401408);
  char* regionA = take(51380224);   // xt (alive through conv_ctx)
  unsigned short* qbuf = (unsigned short*)take(51380224);
  char* regionK = take(51380224);   // KexpT (alive through conv_ctx)
  char* regionV = take(51380224);   // VT (alive through conv_ctx) -> reused
  float* x1part = (float*)take(25690112);   // branch-1 partials NSK=16
  if (off > ws_size) return;

  unsigned short* xt    = (unsigned short*)regionA;
  unsigned short* KexpT = (unsigned short*)regionK;
  unsigned short* VT = (unsigned short*)regionV;
  unsigned short* Gmat = (unsigned short*)regionV;
  unsigned short* x1g  = (unsigned short*)(regionV + 4194304);
  unsigned short* x2g  = (unsigned short*)(regionV + 4997120);
  float* kexp1 = (float*)(regionV + 8208384);
  float* vraw1 = (float*)(regionV + 9011200);
  float* vmod1 = (float*)(regionV + 9814016);
  float* kexp2 = (float*)(regionV + 10616832);
  float* vraw2 = (float*)(regionV + 13828096);
  float* vmod2 = (float*)(regionV + 17039360);
  unsigned short* ctxcomb = (unsigned short*)d_out;                 // 8.4 MB
  float* ctxpart = (float*)((char*)d_out + 8388608);                // 58.7 MB
  float* x2part  = (float*)((char*)d_out + 67108864);               // 25.7 MB

  hipMemsetAsync(s_k, 0, 32768, stream);
  prep_trans_kernel<<<8320, 256, 0, stream>>>(x, xt,
                                              Wq, Wk, Wv, Wkv1, Wkv2, sr1w, sr2w,
                                              rpw, rpb, rp12w, rp12b, dww,
                                              WqT, WkT, WvT, Wkv1T, Wkv2T, srw1, srw2,
                                              Acomb, bias_out);
  qkv3_kernel<<<1568, 256, 0, stream>>>(xt, WqT, WkT, WvT, bq, bk, bv,
                                        qbuf, KexpT, VT, s_q, s_k);
  conv_ctx_kernel<<<392+400+896, 256, 0, stream>>>(xt, srw1, srw2,
                                                   x1part, x2part, KexpT, VT, ctxpart);
  red_ln_kernel<<<7840+2048, 256, 0, stream>>>(x1part, x2part, sr1b, sr2b,
                                               ln1g, ln1b, ln2g, ln2b, x1g, x2g,
                                               ctxpart, s_k, ctxcomb);
  kv_both_kernel<<<246, 256, 0, stream>>>(x1g, Wkv1T, bkv1, kexp1, vraw1,
                                          x2g, Wkv2T, bkv2, kexp2, vraw2);
  dwconv_both_kernel<<<3920, 256, 0, stream>>>(vraw1, lc1w, lc1b, vmod1,
                                               vraw2, lc2w, lc2b, vmod2);
  ctxbr_both_kernel<<<dim3(32,64), 512, 0, stream>>>(kexp1, vmod1, kexp2, vmod2, ctxcomb);
  gmat_kernel<<<dim3(32,2,2), 256, 0, stream>>>(Acomb, ctxcomb, Gmat);
  final_kernel<<<dim3(32,2,49), 256, 0, stream>>>(Gmat, qbuf, bias_out, s_q, (float*)d_out);
}